// Round 2
// baseline (148.181 us; speedup 1.0000x reference)
//
#include <hip/hip_runtime.h>

// N=32, CIN=64, COUT=128, K=4, H=W=64
#define Nn     32
#define CIN    64
#define COUT   128
#define HWVOL  4096                 // H*W
#define PLANES (Nn * CIN)           // 2048
#define OHW_INV (1.0f / 4489.0f)    // 1/67^2

// Single fused kernel: each block reduces one (n,ci) plane of x; the LAST
// block (atomic ticket) additionally computes Sw, pooled, and the logsumexp.
__global__ __launch_bounds__(256) void fused_kernel(
    const float* __restrict__ x,
    const float* __restrict__ w,
    const float* __restrict__ conv_bias,
    const float* __restrict__ extra_bias,
    float* __restrict__ Sx,            // d_ws: PLANES floats
    unsigned int* __restrict__ counter,
    float* __restrict__ out)
{
    const int g = blockIdx.x;
    const int t = threadIdx.x;

    // ---------------- phase 1: reduce plane g (4096 floats) ----------------
    const float4* xp = (const float4*)(x + (size_t)g * HWVOL);
    float acc = 0.0f;
#pragma unroll
    for (int j = 0; j < 4; ++j) {
        float4 v = xp[t + 256 * j];
        acc += (v.x + v.y) + (v.z + v.w);
    }
#pragma unroll
    for (int off = 32; off > 0; off >>= 1)
        acc += __shfl_down(acc, off, 64);

    __shared__ float part[4];
    __shared__ int   is_last;
    if ((t & 63) == 0) part[t >> 6] = acc;
    __syncthreads();
    if (t == 0) {
        Sx[g] = (part[0] + part[1]) + (part[2] + part[3]);
        __threadfence();                       // publish Sx (device scope)
        unsigned int old = atomicAdd(counter, 1u);
        is_last = (old == PLANES - 1) ? 1 : 0;
    }
    __syncthreads();
    if (!is_last) return;
    __threadfence();                           // acquire all Sx stores

    // ---------------- phase 2 (one block): Sw, pooled, logsumexp -----------
    __shared__ float sw[CIN * COUT];           // 32 KB
    __shared__ float sxs[PLANES];              // 8 KB
    __shared__ float pooled[Nn * COUT];        // 16 KB
    __shared__ float bias[COUT];               // 0.5 KB

    // all Sx -> LDS
#pragma unroll
    for (int j = 0; j < PLANES / 256; ++j)
        sxs[t + 256 * j] = Sx[t + 256 * j];
    // combined bias -> LDS
    if (t < COUT) bias[t] = conv_bias[t] + extra_bias[t];
    // Sw: 8192 sums of 16 contiguous taps
#pragma unroll
    for (int j = 0; j < (CIN * COUT) / 256; ++j) {
        const int o = j * 256 + t;
        const float4* wp = (const float4*)(w + (size_t)o * 16);
        float4 a = wp[0], b = wp[1], c = wp[2], d = wp[3];
        sw[o] = (((a.x + a.y) + (a.z + a.w)) + ((b.x + b.y) + (b.z + b.w))) +
                (((c.x + c.y) + (c.z + c.w)) + ((d.x + d.y) + (d.z + d.w)));
    }
    __syncthreads();

    // pooled[n][co]; lanes share n (sxs broadcast), co consecutive (2-way LDS, free)
#pragma unroll
    for (int j = 0; j < (Nn * COUT) / 256; ++j) {
        const int idx = j * 256 + t;
        const int n  = idx >> 7;
        const int co = idx & (COUT - 1);
        float a = 0.0f;
#pragma unroll
        for (int ci = 0; ci < CIN; ++ci)
            a = fmaf(sxs[n * CIN + ci], sw[ci * COUT + co], a);
        pooled[idx] = a * OHW_INV + bias[co];
    }
    __syncthreads();

    // logsumexp per n: 8 threads/n, 16 co each, online-softmax shuffle combine
    {
        const int n = t >> 3;                  // 0..31
        const int r = t & 7;
        float m = -3.4e38f, l = 0.0f;
#pragma unroll
        for (int j = 0; j < 16; ++j) {
            float v = pooled[n * COUT + r * 16 + j];
            float mn = fmaxf(m, v);
            l = l * __expf(m - mn) + __expf(v - mn);
            m = mn;
        }
#pragma unroll
        for (int off = 1; off < 8; off <<= 1) {
            float m2 = __shfl_xor(m, off, 64);
            float l2 = __shfl_xor(l, off, 64);
            float mn = fmaxf(m, m2);
            l = l * __expf(m - mn) + l2 * __expf(m2 - mn);
            m = mn;
        }
        if (r == 0) out[n] = 10.0f * (m + logf(l));
    }
}

extern "C" void kernel_launch(void* const* d_in, const int* in_sizes, int n_in,
                              void* d_out, int out_size, void* d_ws, size_t ws_size,
                              hipStream_t stream) {
    const float* x          = (const float*)d_in[0];
    const float* weight     = (const float*)d_in[1];
    const float* conv_bias  = (const float*)d_in[2];
    const float* extra_bias = (const float*)d_in[3];
    float* out = (float*)d_out;

    float* Sx = (float*)d_ws;                          // 2048 floats
    unsigned int* counter = (unsigned int*)((char*)d_ws + PLANES * sizeof(float));

    hipMemsetAsync(counter, 0, sizeof(unsigned int), stream);
    fused_kernel<<<PLANES, 256, 0, stream>>>(x, weight, conv_bias, extra_bias,
                                             Sx, counter, out);
}

// Round 3
// 78.929 us; speedup vs baseline: 1.8774x; 1.8774x over previous
//
#include <hip/hip_runtime.h>

// N=32, CIN=64, COUT=128, K=4, H=W=64
#define Nn     32
#define CIN    64
#define COUT   128
#define HWVOL  4096                 // H*W
#define PLANES (Nn * CIN)           // 2048
#define WBLKS  ((CIN * COUT) / 256) // 32 blocks for the weight sums
#define OHW_INV (1.0f / 4489.0f)    // 1/67^2

// ---------------------------------------------------------------------------
// Stage 1 (single launch, no internal dependency):
//   blocks [0, 2048):    Sx[g] = sum of x-plane g   (16 KB coalesced read)
//   blocks [2048, 2080): Sw[o] = sum of 16 kernel taps, o = (b-2048)*256 + t
// Small LDS (16 B) -> full occupancy for the streaming phase.
// ---------------------------------------------------------------------------
__global__ __launch_bounds__(256) void stage1_kernel(
    const float* __restrict__ x,
    const float* __restrict__ w,
    float* __restrict__ Sx,
    float* __restrict__ Sw)
{
    const int b = blockIdx.x;
    const int t = threadIdx.x;

    if (b < PLANES) {
        const float4* xp = (const float4*)(x + (size_t)b * HWVOL);
        float acc = 0.0f;
#pragma unroll
        for (int j = 0; j < 4; ++j) {
            float4 v = xp[t + 256 * j];
            acc += (v.x + v.y) + (v.z + v.w);
        }
#pragma unroll
        for (int off = 32; off > 0; off >>= 1)
            acc += __shfl_down(acc, off, 64);
        __shared__ float part[4];
        if ((t & 63) == 0) part[t >> 6] = acc;
        __syncthreads();
        if (t == 0) Sx[b] = (part[0] + part[1]) + (part[2] + part[3]);
    } else {
        const int o = (b - PLANES) * 256 + t;   // 0..8191
        const float4* wp = (const float4*)(w + (size_t)o * 16);
        float4 a = wp[0], c = wp[1], d = wp[2], e = wp[3];
        Sw[o] = (((a.x + a.y) + (a.z + a.w)) + ((c.x + c.y) + (c.z + c.w))) +
                (((d.x + d.y) + (d.z + d.w)) + ((e.x + e.y) + (e.z + e.w)));
    }
}

// ---------------------------------------------------------------------------
// Stage 2: one block per image n, 128 threads = one per co.
//   pooled[co] = (sum_ci Sx[n,ci]*Sw[ci,co]) / 4489 + conv_bias + extra_bias
//   out[n]    = 10 * logsumexp_co(pooled)
// Sw reads coalesced (stride COUT across lanes); ~32 KB per block, L2-hot.
// ---------------------------------------------------------------------------
__global__ __launch_bounds__(128) void final_kernel(
    const float* __restrict__ Sx,
    const float* __restrict__ Sw,
    const float* __restrict__ conv_bias,
    const float* __restrict__ extra_bias,
    float* __restrict__ out)
{
    const int n  = blockIdx.x;
    const int co = threadIdx.x;
    __shared__ float sxs[CIN];
    if (co < CIN) sxs[co] = Sx[n * CIN + co];
    __syncthreads();

    float acc = 0.0f;
#pragma unroll
    for (int ci = 0; ci < CIN; ++ci)
        acc = fmaf(sxs[ci], Sw[ci * COUT + co], acc);

    const float pooled = acc * OHW_INV + conv_bias[co] + extra_bias[co];

    // logsumexp over 128 lanes: 2 waves -> LDS combine
    float m = pooled;
#pragma unroll
    for (int off = 32; off > 0; off >>= 1)
        m = fmaxf(m, __shfl_xor(m, off, 64));
    __shared__ float wm[2];
    if ((co & 63) == 0) wm[co >> 6] = m;
    __syncthreads();
    m = fmaxf(wm[0], wm[1]);

    float e = __expf(pooled - m);
#pragma unroll
    for (int off = 32; off > 0; off >>= 1)
        e += __shfl_xor(e, off, 64);
    __shared__ float wl[2];
    if ((co & 63) == 0) wl[co >> 6] = e;
    __syncthreads();
    if (co == 0) out[n] = 10.0f * (m + logf(wl[0] + wl[1]));
}

extern "C" void kernel_launch(void* const* d_in, const int* in_sizes, int n_in,
                              void* d_out, int out_size, void* d_ws, size_t ws_size,
                              hipStream_t stream) {
    const float* x          = (const float*)d_in[0];
    const float* weight     = (const float*)d_in[1];
    const float* conv_bias  = (const float*)d_in[2];
    const float* extra_bias = (const float*)d_in[3];
    float* out = (float*)d_out;

    float* Sx = (float*)d_ws;          // 2048 floats
    float* Sw = Sx + PLANES;           // 8192 floats

    stage1_kernel<<<PLANES + WBLKS, 256, 0, stream>>>(x, weight, Sx, Sw);
    final_kernel<<<Nn, 128, 0, stream>>>(Sx, Sw, conv_bias, extra_bias, out);
}